// Round 25
// baseline (128.744 us; speedup 1.0000x reference)
//
#include <hip/hip_runtime.h>
#include <hip/hip_bf16.h>

#define D_MODEL 1024
#define NHEADS 16
#define DEPTH 64
#define BATCH 2
#define SEQ 2048
#define NTOK (BATCH * SEQ)   // 4096

// log2(e): scores computed in log2 domain (exp -> exp2)
#define QSCALE 0.180336884f   /* 0.125 * log2(e) */
#define DEFER_THR 11.5415603f /* 8 * log2(e) */

typedef short bf16x8 __attribute__((ext_vector_type(8)));
typedef float f32x4 __attribute__((ext_vector_type(4)));
typedef float f32x16 __attribute__((ext_vector_type(16)));
typedef unsigned short ushortx8 __attribute__((ext_vector_type(8)));
typedef unsigned uint2v __attribute__((ext_vector_type(2)));

using gas_ptr = const __attribute__((address_space(1))) unsigned int*;
using las_ptr = __attribute__((address_space(3))) unsigned int*;

__device__ __forceinline__ unsigned short f2bf(float f) {
    union { float f; unsigned u; } v; v.f = f;
    unsigned r = v.u + 0x7fffu + ((v.u >> 16) & 1u);
    return (unsigned short)(r >> 16);
}

__device__ __forceinline__ unsigned cvtpk(float lo, float hi) {
    unsigned r;
    asm("v_cvt_pk_bf16_f32 %0, %1, %2" : "=v"(r) : "v"(lo), "v"(hi));
    return r;
}

__device__ __forceinline__ uint2v pls(unsigned a, unsigned b) {
    return __builtin_amdgcn_permlane32_swap(a, b, false, false);
}

__device__ __forceinline__ void gload16(const void* g, void* l) {
    __builtin_amdgcn_global_load_lds((gas_ptr)g, (las_ptr)l, 16, 0, 0);
}

// ---------------- prep: fp32 -> bf16 for activations + weights ----------------
__global__ __launch_bounds__(256) void convert_bf16(
    const float* __restrict__ q, const float* __restrict__ k, const float* __restrict__ v,
    const float* __restrict__ wq, const float* __restrict__ wk,
    const float* __restrict__ wv, const float* __restrict__ wo,
    unsigned short* __restrict__ qb, unsigned short* __restrict__ kb,
    unsigned short* __restrict__ vb,
    unsigned short* __restrict__ wqb, unsigned short* __restrict__ wkb,
    unsigned short* __restrict__ wvb, unsigned short* __restrict__ wob)
{
    const int ACT = (NTOK * D_MODEL) / 8;
    const int WT  = (D_MODEL * D_MODEL) / 8;
    const int total = 3 * ACT + 4 * WT;
    for (int i = blockIdx.x * 256 + threadIdx.x; i < total; i += gridDim.x * 256) {
        const float* s; unsigned short* d; int off; float sc = 1.f;
        if (i < ACT)            { s = q; d = qb; off = i; }
        else if (i < 2 * ACT)   { s = k; d = kb; off = i - ACT; }
        else if (i < 3 * ACT)   { s = v; d = vb; off = i - 2 * ACT; }
        else {
            int j = i - 3 * ACT;
            int wsel = j >> 17;  off = j & (WT - 1);
            s = (wsel == 0) ? wq : (wsel == 1) ? wk : (wsel == 2) ? wv : wo;
            d = (wsel == 0) ? wqb : (wsel == 1) ? wkb : (wsel == 2) ? wvb : wob;
            if (wsel == 0) sc = QSCALE;
        }
        float4 a = ((const float4*)s)[off * 2];
        float4 b = ((const float4*)s)[off * 2 + 1];
        ushortx8 r;
        r[0] = f2bf(a.x * sc); r[1] = f2bf(a.y * sc);
        r[2] = f2bf(a.z * sc); r[3] = f2bf(a.w * sc);
        r[4] = f2bf(b.x * sc); r[5] = f2bf(b.y * sc);
        r[6] = f2bf(b.z * sc); r[7] = f2bf(b.w * sc);
        ((ushortx8*)d)[off] = r;
    }
}

// ---- bf16 GEMM: BK=32, 3-buffer rotation, 2-deep prefetch, counted vmcnt ----
// Grid: (rowpanels, npanels, z) -> A-panel XCD affinity (id%8 == rowpanel%8).
template<int IT, int DEST, bool QKV>
__global__ __launch_bounds__(256) void gemm_bf16(
    const unsigned short* __restrict__ A0, const unsigned short* __restrict__ A1,
    const unsigned short* __restrict__ A2,
    const unsigned short* __restrict__ B0, const unsigned short* __restrict__ B1,
    const unsigned short* __restrict__ B2,
    const float* __restrict__ bias0, const float* __restrict__ bias1,
    const float* __restrict__ bias2,
    void* __restrict__ C0, void* __restrict__ C1, void* __restrict__ C2,
    int M, int N, int K)
{
    constexpr int BM = IT * 32;
    constexpr int WROWS = IT * 16;
    constexpr int ASZ = BM * 32;
    __shared__ unsigned short As[3 * ASZ];
    __shared__ unsigned short Bs[3 * 4096];

    const unsigned short* A = A0; const unsigned short* Bw = B0;
    const float* bias = bias0;    void* Cp = C0;
    float bsc = 1.f;
    int zz = 0;
    if (QKV) {
        zz = blockIdx.z;
        if (zz == 0) bsc = QSCALE;
        if (zz == 1) { A = A1; Bw = B1; bias = bias1; Cp = C1; }
        else if (zz == 2) { A = A2; Bw = B2; bias = bias2; Cp = C2; }
    }

    const int tid  = threadIdx.x;
    const int lane = tid & 63;
    const int w    = tid >> 6;
    const int wu   = __builtin_amdgcn_readfirstlane(w);
    const int wr   = w >> 1, wc = w & 1;
    const int lr   = lane & 15, lg = lane >> 4;

    const int row0 = blockIdx.x * BM;
    const int n0   = blockIdx.y * 128;

    const int cA0 = wu * 64 + lane;
    const unsigned short* gA0 = A + (size_t)(row0 + (cA0 >> 2)) * K + (cA0 & 3) * 8;
    const unsigned short* gA1 = nullptr;
    if (IT == 4) {
        const int cA1 = 256 + cA0;
        gA1 = A + (size_t)(row0 + (cA1 >> 2)) * K + (cA1 & 3) * 8;
    }
    const unsigned short* gB0 = Bw + (size_t)(n0 + (cA0 >> 2)) * K + (cA0 & 3) * 8;
    const unsigned short* gB1;
    {
        const int cB1 = 256 + cA0;
        gB1 = Bw + (size_t)(n0 + (cB1 >> 2)) * K + (cB1 & 3) * 8;
    }

    auto STAGE = [&](int kt, int buf) {
        gload16(gA0 + kt, &As[buf * ASZ + wu * 512]);
        if (IT == 4) gload16(gA1 + kt, &As[buf * ASZ + 2048 + wu * 512]);
        gload16(gB0 + kt, &Bs[buf * 4096 + wu * 512]);
        gload16(gB1 + kt, &Bs[buf * 4096 + 2048 + wu * 512]);
    };

    f32x4 acc[IT][4];
    for (int i = 0; i < IT; ++i)
        for (int j = 0; j < 4; ++j)
            for (int r = 0; r < 4; ++r) acc[i][j][r] = 0.f;

    const int NT = K / 32;
    STAGE(0, 0);
    STAGE(32, 1);

    int cur = 0;
    for (int t = 0; t < NT; ++t) {
        if (t < NT - 1) {
            if constexpr (IT == 4)
                asm volatile("s_waitcnt vmcnt(4)" ::: "memory");
            else
                asm volatile("s_waitcnt vmcnt(3)" ::: "memory");
        } else {
            asm volatile("s_waitcnt vmcnt(0)" ::: "memory");
        }
        __builtin_amdgcn_s_barrier();
        __builtin_amdgcn_sched_barrier(0);

        bf16x8 af[IT], bfr[4];
#pragma unroll
        for (int i = 0; i < IT; ++i)
            af[i] = *(const bf16x8*)&As[cur * ASZ + (wr * WROWS + i * 16 + lr) * 32 + lg * 8];
#pragma unroll
        for (int j = 0; j < 4; ++j)
            bfr[j] = *(const bf16x8*)&Bs[cur * 4096 + (wc * 64 + j * 16 + lr) * 32 + lg * 8];

        if (t + 2 < NT) {
            int nb = cur + 2; if (nb >= 3) nb -= 3;
            STAGE((t + 2) * 32, nb);
        }

#pragma unroll
        for (int i = 0; i < IT; ++i)
#pragma unroll
            for (int j = 0; j < 4; ++j)
                acc[i][j] = __builtin_amdgcn_mfma_f32_16x16x32_bf16(
                    af[i], bfr[j], acc[i][j], 0, 0, 0);

        cur = (cur == 2) ? 0 : cur + 1;
    }

    for (int i = 0; i < IT; ++i) {
        for (int j = 0; j < 4; ++j) {
            int gcol = n0 + wc * 64 + j * 16 + lr;
            float bv = bias[gcol] * bsc;
            int s0full = row0 + wr * WROWS + i * 16 + lg * 4;
            if (QKV && zz == 1) {
                int b_ = s0full >> 11, sr = s0full & (SEQ - 1);
                int h_ = gcol >> 6, dh = gcol & 63;
                int jt_ = sr >> 6, t0 = sr & 63;
                int tb_ = t0 >> 5, m0 = t0 & 31;
                int dk_ = dh >> 4, hi_ = (dh >> 3) & 1, e_ = dh & 7;
                unsigned short* Kf = (unsigned short*)Cp;
                size_t base = ((size_t)(b_ * NHEADS + h_) * (SEQ >> 6) + jt_) * 4096
                            + (size_t)((tb_ * 4 + dk_) * 64 + hi_ * 32) * 8 + e_;
#pragma unroll
                for (int r = 0; r < 4; ++r)
                    Kf[base + (size_t)(m0 + r) * 8] = f2bf(acc[i][j][r] + bv);
            } else if (QKV && zz == 2) {
                int b_ = s0full >> 11, sr = s0full & (SEQ - 1);
                int h_ = gcol >> 6, dh = gcol & 63;
                int jt_ = sr >> 6, t0 = sr & 63;
                int ts_ = t0 >> 4, hi_ = (t0 >> 3) & 1, e0 = t0 & 7;
                int dblk = dh >> 5, m_ = dh & 31;
                unsigned w0 = (unsigned)f2bf(acc[i][j][0] + bv)
                            | ((unsigned)f2bf(acc[i][j][1] + bv) << 16);
                unsigned w1 = (unsigned)f2bf(acc[i][j][2] + bv)
                            | ((unsigned)f2bf(acc[i][j][3] + bv) << 16);
                unsigned long long pk = (unsigned long long)w0
                                      | ((unsigned long long)w1 << 32);
                unsigned short* Vf = (unsigned short*)Cp;
                size_t idx = ((size_t)(b_ * NHEADS + h_) * (SEQ >> 6) + jt_) * 4096
                           + (size_t)((dblk * 4 + ts_) * 64 + hi_ * 32 + m_) * 8 + e0;
                *(unsigned long long*)&Vf[idx] = pk;
            } else if (DEST == 0) {
#pragma unroll
                for (int r = 0; r < 4; ++r) {
                    int grow = s0full + r;
                    float val = acc[i][j][r] + bv;
                    int b_ = grow >> 11, s = grow & (SEQ - 1);
                    int h_ = gcol >> 6, dh = gcol & 63;
                    ((unsigned short*)Cp)[(((size_t)b_ * NHEADS + h_) * SEQ + s) * DEPTH + dh]
                        = f2bf(val);
                }
            } else {
#pragma unroll
                for (int r = 0; r < 4; ++r) {
                    int grow = s0full + r;
                    ((float*)Cp)[(size_t)grow * N + gcol] = acc[i][j][r] + bv;
                }
            }
        }
    }
}

// -------- causal flash attention: 2 waves/block KV-split, 32 q-rows ----------
// round-23 config + V double-buffered in regs; launch_bounds(128,1) so the
// +64 VGPR V-buffer stays in registers (round-24's (128,2) spilled).
#define KLOAD(JT, KF)                                                          \
{                                                                              \
    const unsigned short* Kt_ = Kb + (size_t)(JT) * 4096;                      \
    _Pragma("unroll")                                                          \
    for (int f_ = 0; f_ < 8; ++f_)                                             \
        KF[f_] = *(const bf16x8*)&Kt_[(size_t)f_ * 512 + lane * 8];            \
}

#define VLOAD(JT, VF)                                                          \
{                                                                              \
    const unsigned short* Vt_ = Vb + (size_t)(JT) * 4096;                      \
    _Pragma("unroll")                                                          \
    for (int f_ = 0; f_ < 8; ++f_)                                             \
        VF[f_] = *(const bf16x8*)&Vt_[(size_t)f_ * 512 + lane * 8];            \
}

#define TILE_BODY(KC, VC, KN, VN)                                              \
{                                                                              \
    if (jt + 2 < ntiles) { KLOAD(jt + 2, KN) VLOAD(jt + 2, VN) }               \
    f32x16 st[2];                                                              \
    __builtin_amdgcn_s_setprio(1);                                             \
    _Pragma("unroll")                                                          \
    for (int tb = 0; tb < 2; ++tb) {                                           \
        f32x16 a;                                                              \
        _Pragma("unroll") for (int r = 0; r < 16; ++r) a[r] = 0.f;             \
        _Pragma("unroll")                                                      \
        for (int dk = 0; dk < 4; ++dk)                                         \
            a = __builtin_amdgcn_mfma_f32_32x32x16_bf16(KC[tb * 4 + dk], qf[dk], a, 0, 0, 0); \
        st[tb] = a;                                                            \
    }                                                                          \
    __builtin_amdgcn_s_setprio(0);                                             \
    if (jt == ntiles - 1) {                                                    \
        _Pragma("unroll")                                                      \
        for (int tb = 0; tb < 2; ++tb)                                         \
            _Pragma("unroll")                                                  \
            for (int r = 0; r < 16; ++r) {                                     \
                int t = jt * 64 + tb * 32 + (r & 3) + 8 * (r >> 2) + 4 * hi;   \
                if (t > qr0 + m) st[tb][r] = -1e9f;                            \
            }                                                                  \
    }                                                                          \
    float tmx[16];                                                             \
    _Pragma("unroll")                                                          \
    for (int r = 0; r < 16; ++r) tmx[r] = fmaxf(st[0][r], st[1][r]);           \
    _Pragma("unroll")                                                          \
    for (int sft = 8; sft; sft >>= 1)                                          \
        _Pragma("unroll")                                                      \
        for (int r = 0; r < 8; ++r)                                            \
            if (r < sft) tmx[r] = fmaxf(tmx[r], tmx[r + sft]);                 \
    float tmax;                                                                \
    {                                                                          \
        union { float f; unsigned u; } cu_; cu_.f = tmx[0];                    \
        uint2v rr_ = pls(cu_.u, cu_.u);                                        \
        union { unsigned u; float f; } a_, b_; a_.u = rr_[0]; b_.u = rr_[1];   \
        tmax = fmaxf(a_.f, b_.f);                                              \
    }                                                                          \
    if (!__all(tmax <= mrun + DEFER_THR)) {                                    \
        float mnew = fmaxf(mrun, tmax);                                        \
        float sc = exp2f(mrun - mnew);                                         \
        mrun = mnew; lrun *= sc;                                               \
        if (hi == 0) scbw[m] = sc;                                             \
        f32x4 s4[4];                                                           \
        _Pragma("unroll")                                                      \
        for (int g = 0; g < 4; ++g) s4[g] = *(f32x4*)&scbw[g * 8 + hi * 4];    \
        _Pragma("unroll")                                                      \
        for (int r = 0; r < 16; ++r) {                                         \
            float f = s4[r >> 2][r & 3];                                       \
            o0[r] *= f; o1[r] *= f;                                            \
        }                                                                      \
    }                                                                          \
    _Pragma("unroll")                                                          \
    for (int tb = 0; tb < 2; ++tb)                                             \
        _Pragma("unroll")                                                      \
        for (int r = 0; r < 16; ++r)                                           \
            st[tb][r] = exp2f(st[tb][r] - mrun);                               \
    float s16[16];                                                             \
    _Pragma("unroll")                                                          \
    for (int r = 0; r < 16; ++r) s16[r] = st[0][r] + st[1][r];                 \
    _Pragma("unroll")                                                          \
    for (int sft = 8; sft; sft >>= 1)                                          \
        _Pragma("unroll")                                                      \
        for (int r = 0; r < 8; ++r)                                            \
            if (r < sft) s16[r] += s16[r + sft];                               \
    {                                                                          \
        union { float f; unsigned u; } cu_; cu_.f = s16[0];                    \
        uint2v rr_ = pls(cu_.u, cu_.u);                                        \
        union { unsigned u; float f; } a_, b_; a_.u = rr_[0]; b_.u = rr_[1];   \
        lrun += a_.f + b_.f;                                                   \
    }                                                                          \
    unsigned pkw[8][2];                                                        \
    _Pragma("unroll")                                                          \
    for (int G = 0; G < 8; ++G) {                                              \
        const int tb = G >> 2, g = G & 3;                                      \
        pkw[G][0] = cvtpk(st[tb][4 * g + 0], st[tb][4 * g + 1]);               \
        pkw[G][1] = cvtpk(st[tb][4 * g + 2], st[tb][4 * g + 3]);               \
    }                                                                          \
    __builtin_amdgcn_s_setprio(1);                                             \
    _Pragma("unroll")                                                          \
    for (int ts = 0; ts < 4; ++ts) {                                           \
        uint2v s0_ = pls(pkw[2 * ts][0], pkw[2 * ts + 1][0]);                  \
        uint2v s1_ = pls(pkw[2 * ts][1], pkw[2 * ts + 1][1]);                  \
        union { unsigned u[4]; bf16x8 v; } uu;                                 \
        uu.u[0] = s0_[0]; uu.u[1] = s1_[0]; uu.u[2] = s0_[1]; uu.u[3] = s1_[1]; \
        o0 = __builtin_amdgcn_mfma_f32_32x32x16_bf16(uu.v, VC[ts], o0, 0, 0, 0); \
        o1 = __builtin_amdgcn_mfma_f32_32x32x16_bf16(uu.v, VC[4 + ts], o1, 0, 0, 0); \
    }                                                                          \
    __builtin_amdgcn_s_setprio(0);                                             \
}

__global__ __launch_bounds__(128, 1) void attn_wave(
    const unsigned short* __restrict__ Qh, const unsigned short* __restrict__ Kh,
    const unsigned short* __restrict__ Vt, unsigned short* __restrict__ ctx)
{
    __shared__ __align__(16) float scb[2][32];
    __shared__ __align__(16) float mlbuf[2][2][32];
    __shared__ __align__(16) float c0b[32], c1b[32], invb[32];
    __shared__ __align__(16) float osh0[16][64], osh1[16][64];

    const int tid  = threadIdx.x;
    const int ww   = tid >> 6;
    const int lane = tid & 63;
    const int m    = lane & 31;
    const int hi   = lane >> 5;
    float* scbw = scb[ww];

    const int bid  = blockIdx.x;
    const int bh   = bid & 31;
    const int qb   = 63 - (bid >> 5);
    const int qr0  = qb * 32;

    const int b = bh >> 4, h = bh & 15;
    const unsigned short* Qb = Qh + ((size_t)bh * SEQ + qr0) * DEPTH;
    const unsigned short* Kb = Kh + (size_t)bh * SEQ * DEPTH;
    const unsigned short* Vb = Vt + (size_t)bh * SEQ * DEPTH;

    bf16x8 qf[4];
#pragma unroll
    for (int dk = 0; dk < 4; ++dk)
        qf[dk] = *(const bf16x8*)&Qb[(size_t)m * DEPTH + dk * 16 + hi * 8];

    f32x16 o0, o1;
#pragma unroll
    for (int r = 0; r < 16; ++r) { o0[r] = 0.f; o1[r] = 0.f; }
    float mrun = -1e30f, lrun = 0.f;

    const int ntiles = (qb >> 1) + 1;
    bf16x8 kfA[8], kfB[8], vfA[8], vfB[8];

    int jt = ww;
    if (jt < ntiles) {
        KLOAD(jt, kfA) VLOAD(jt, vfA)
        while (true) {
            TILE_BODY(kfA, vfA, kfB, vfB)
            jt += 2; if (jt >= ntiles) break;
            TILE_BODY(kfB, vfB, kfA, vfA)
            jt += 2; if (jt >= ntiles) break;
        }
    }

    if (hi == 0) { mlbuf[ww][0][m] = mrun; mlbuf[ww][1][m] = lrun; }
    __syncthreads();
    if (ww == 0 && hi == 0) {
        float m0 = mlbuf[0][0][m], l0 = mlbuf[0][1][m];
        float m1 = mlbuf[1][0][m], l1 = mlbuf[1][1][m];
        float M  = fmaxf(m0, m1);
        float c0 = exp2f(m0 - M), c1 = exp2f(m1 - M);
        c0b[m] = c0; c1b[m] = c1;
        invb[m] = 1.0f / (l0 * c0 + l1 * c1);
    }
    __syncthreads();

    const float* cb = (ww == 0) ? c0b : c1b;
    f32x4 fc[4];
#pragma unroll
    for (int g = 0; g < 4; ++g)
        fc[g] = *(const f32x4*)&cb[g * 8 + hi * 4];
#pragma unroll
    for (int r = 0; r < 16; ++r) {
        float f = fc[r >> 2][r & 3];
        o0[r] *= f; o1[r] *= f;
    }
    if (ww == 0) {
#pragma unroll
        for (int r = 0; r < 16; ++r) { osh0[r][lane] = o0[r]; osh1[r][lane] = o1[r]; }
    }
    __syncthreads();
    if (ww == 1) {
        f32x4 fi[4];
#pragma unroll
        for (int g = 0; g < 4; ++g)
            fi[g] = *(const f32x4*)&invb[g * 8 + hi * 4];
#pragma unroll
        for (int r = 0; r < 16; ++r) {
            float inv = fi[r >> 2][r & 3];
            int ml = (r & 3) + 8 * (r >> 2) + 4 * hi;
            size_t rowbase = ((size_t)b * SEQ + qr0 + ml) * D_MODEL + h * DEPTH;
            ctx[rowbase + m]      = f2bf((o0[r] + osh0[r][lane]) * inv);
            ctx[rowbase + 32 + m] = f2bf((o1[r] + osh1[r][lane]) * inv);
        }
    }
}

extern "C" void kernel_launch(void* const* d_in, const int* in_sizes, int n_in,
                              void* d_out, int out_size, void* d_ws, size_t ws_size,
                              hipStream_t stream) {
    const float* v  = (const float*)d_in[0];
    const float* k  = (const float*)d_in[1];
    const float* q  = (const float*)d_in[2];
    // d_in[3] = mask (causal, implemented analytically)
    const float* Wq = (const float*)d_in[4];
    const float* bq = (const float*)d_in[5];
    const float* Wk = (const float*)d_in[6];
    const float* bk = (const float*)d_in[7];
    const float* Wv = (const float*)d_in[8];
    const float* bv = (const float*)d_in[9];
    const float* Wo = (const float*)d_in[10];
    const float* bo = (const float*)d_in[11];

    char* ws = (char*)d_ws;
    const size_t MB = 1024 * 1024;
    unsigned short* Qb  = (unsigned short*)(ws + 0);        // 8 MB (aliased by ctx)
    unsigned short* Kb  = (unsigned short*)(ws + 8  * MB);
    unsigned short* Vb  = (unsigned short*)(ws + 16 * MB);
    unsigned short* Wqb = (unsigned short*)(ws + 24 * MB);  // 2 MB each
    unsigned short* Wkb = (unsigned short*)(ws + 26 * MB);
    unsigned short* Wvb = (unsigned short*)(ws + 28 * MB);
    unsigned short* Wob = (unsigned short*)(ws + 30 * MB);
    unsigned short* Qh  = (unsigned short*)(ws + 32 * MB);  // 8 MB each
    unsigned short* Kh  = (unsigned short*)(ws + 40 * MB);
    unsigned short* Vtt = (unsigned short*)(ws + 48 * MB);
    unsigned short* ctx = Qb;   // Qb dead once projections finish

    convert_bf16<<<2048, 256, 0, stream>>>(q, k, v, Wq, Wk, Wv, Wo,
                                           Qb, Kb, Vb, Wqb, Wkb, Wvb, Wob);

    // QKV projections: grid (rowpanels=32, npanels=8, 3) -> A-panel XCD affinity
    gemm_bf16<4, 0, true><<<dim3(32, 8, 3), 256, 0, stream>>>(
        Qb, Kb, Vb, Wqb, Wkb, Wvb, bq, bk, bv,
        (void*)Qh, (void*)Kh, (void*)Vtt, NTOK, D_MODEL, D_MODEL);

    attn_wave<<<dim3(2048), 128, 0, stream>>>(Qh, Kh, Vtt, ctx);

    // output projection: grid (rowpanels=64, npanels=8)
    gemm_bf16<2, 1, false><<<dim3(64, 8), 256, 0, stream>>>(
        ctx, nullptr, nullptr, Wob, nullptr, nullptr, bo, nullptr, nullptr,
        d_out, nullptr, nullptr, NTOK, D_MODEL, D_MODEL);
}

// Round 26
// 111.854 us; speedup vs baseline: 1.1510x; 1.1510x over previous
//
#include <hip/hip_runtime.h>
#include <hip/hip_bf16.h>

#define D_MODEL 1024
#define NHEADS 16
#define DEPTH 64
#define BATCH 2
#define SEQ 2048
#define NTOK (BATCH * SEQ)   // 4096

// log2(e): scores computed in log2 domain (exp -> exp2)
#define QSCALE 0.180336884f   /* 0.125 * log2(e) */
#define DEFER_THR 11.5415603f /* 8 * log2(e) */

typedef short bf16x8 __attribute__((ext_vector_type(8)));
typedef float f32x4 __attribute__((ext_vector_type(4)));
typedef float f32x16 __attribute__((ext_vector_type(16)));
typedef unsigned short ushortx8 __attribute__((ext_vector_type(8)));
typedef unsigned uint2v __attribute__((ext_vector_type(2)));

using gas_ptr = const __attribute__((address_space(1))) unsigned int*;
using las_ptr = __attribute__((address_space(3))) unsigned int*;

__device__ __forceinline__ unsigned short f2bf(float f) {
    union { float f; unsigned u; } v; v.f = f;
    unsigned r = v.u + 0x7fffu + ((v.u >> 16) & 1u);
    return (unsigned short)(r >> 16);
}

__device__ __forceinline__ unsigned cvtpk(float lo, float hi) {
    unsigned r;
    asm("v_cvt_pk_bf16_f32 %0, %1, %2" : "=v"(r) : "v"(lo), "v"(hi));
    return r;
}

__device__ __forceinline__ uint2v pls(unsigned a, unsigned b) {
    return __builtin_amdgcn_permlane32_swap(a, b, false, false);
}

__device__ __forceinline__ void gload16(const void* g, void* l) {
    __builtin_amdgcn_global_load_lds((gas_ptr)g, (las_ptr)l, 16, 0, 0);
}

// ---------------- prep: fp32 -> bf16 for activations + weights ----------------
__global__ __launch_bounds__(256) void convert_bf16(
    const float* __restrict__ q, const float* __restrict__ k, const float* __restrict__ v,
    const float* __restrict__ wq, const float* __restrict__ wk,
    const float* __restrict__ wv, const float* __restrict__ wo,
    unsigned short* __restrict__ qb, unsigned short* __restrict__ kb,
    unsigned short* __restrict__ vb,
    unsigned short* __restrict__ wqb, unsigned short* __restrict__ wkb,
    unsigned short* __restrict__ wvb, unsigned short* __restrict__ wob)
{
    const int ACT = (NTOK * D_MODEL) / 8;
    const int WT  = (D_MODEL * D_MODEL) / 8;
    const int total = 3 * ACT + 4 * WT;
    for (int i = blockIdx.x * 256 + threadIdx.x; i < total; i += gridDim.x * 256) {
        const float* s; unsigned short* d; int off; float sc = 1.f;
        if (i < ACT)            { s = q; d = qb; off = i; }
        else if (i < 2 * ACT)   { s = k; d = kb; off = i - ACT; }
        else if (i < 3 * ACT)   { s = v; d = vb; off = i - 2 * ACT; }
        else {
            int j = i - 3 * ACT;
            int wsel = j >> 17;  off = j & (WT - 1);
            s = (wsel == 0) ? wq : (wsel == 1) ? wk : (wsel == 2) ? wv : wo;
            d = (wsel == 0) ? wqb : (wsel == 1) ? wkb : (wsel == 2) ? wvb : wob;
            if (wsel == 0) sc = QSCALE;
        }
        float4 a = ((const float4*)s)[off * 2];
        float4 b = ((const float4*)s)[off * 2 + 1];
        ushortx8 r;
        r[0] = f2bf(a.x * sc); r[1] = f2bf(a.y * sc);
        r[2] = f2bf(a.z * sc); r[3] = f2bf(a.w * sc);
        r[4] = f2bf(b.x * sc); r[5] = f2bf(b.y * sc);
        r[6] = f2bf(b.z * sc); r[7] = f2bf(b.w * sc);
        ((ushortx8*)d)[off] = r;
    }
}

// ---- bf16 GEMM: BK=32, 3-buffer rotation, 2-deep prefetch, counted vmcnt ----
// Grid: (rowpanels, npanels, z) -> A-panel XCD affinity (id%8 == rowpanel%8).
template<int IT, int DEST, bool QKV>
__global__ __launch_bounds__(256) void gemm_bf16(
    const unsigned short* __restrict__ A0, const unsigned short* __restrict__ A1,
    const unsigned short* __restrict__ A2,
    const unsigned short* __restrict__ B0, const unsigned short* __restrict__ B1,
    const unsigned short* __restrict__ B2,
    const float* __restrict__ bias0, const float* __restrict__ bias1,
    const float* __restrict__ bias2,
    void* __restrict__ C0, void* __restrict__ C1, void* __restrict__ C2,
    int M, int N, int K)
{
    constexpr int BM = IT * 32;
    constexpr int WROWS = IT * 16;
    constexpr int ASZ = BM * 32;
    __shared__ unsigned short As[3 * ASZ];
    __shared__ unsigned short Bs[3 * 4096];

    const unsigned short* A = A0; const unsigned short* Bw = B0;
    const float* bias = bias0;    void* Cp = C0;
    float bsc = 1.f;
    int zz = 0;
    if (QKV) {
        zz = blockIdx.z;
        if (zz == 0) bsc = QSCALE;
        if (zz == 1) { A = A1; Bw = B1; bias = bias1; Cp = C1; }
        else if (zz == 2) { A = A2; Bw = B2; bias = bias2; Cp = C2; }
    }

    const int tid  = threadIdx.x;
    const int lane = tid & 63;
    const int w    = tid >> 6;
    const int wu   = __builtin_amdgcn_readfirstlane(w);
    const int wr   = w >> 1, wc = w & 1;
    const int lr   = lane & 15, lg = lane >> 4;

    const int row0 = blockIdx.x * BM;
    const int n0   = blockIdx.y * 128;

    const int cA0 = wu * 64 + lane;
    const unsigned short* gA0 = A + (size_t)(row0 + (cA0 >> 2)) * K + (cA0 & 3) * 8;
    const unsigned short* gA1 = nullptr;
    if (IT == 4) {
        const int cA1 = 256 + cA0;
        gA1 = A + (size_t)(row0 + (cA1 >> 2)) * K + (cA1 & 3) * 8;
    }
    const unsigned short* gB0 = Bw + (size_t)(n0 + (cA0 >> 2)) * K + (cA0 & 3) * 8;
    const unsigned short* gB1;
    {
        const int cB1 = 256 + cA0;
        gB1 = Bw + (size_t)(n0 + (cB1 >> 2)) * K + (cB1 & 3) * 8;
    }

    auto STAGE = [&](int kt, int buf) {
        gload16(gA0 + kt, &As[buf * ASZ + wu * 512]);
        if (IT == 4) gload16(gA1 + kt, &As[buf * ASZ + 2048 + wu * 512]);
        gload16(gB0 + kt, &Bs[buf * 4096 + wu * 512]);
        gload16(gB1 + kt, &Bs[buf * 4096 + 2048 + wu * 512]);
    };

    f32x4 acc[IT][4];
    for (int i = 0; i < IT; ++i)
        for (int j = 0; j < 4; ++j)
            for (int r = 0; r < 4; ++r) acc[i][j][r] = 0.f;

    const int NT = K / 32;
    STAGE(0, 0);
    STAGE(32, 1);

    int cur = 0;
    for (int t = 0; t < NT; ++t) {
        if (t < NT - 1) {
            if constexpr (IT == 4)
                asm volatile("s_waitcnt vmcnt(4)" ::: "memory");
            else
                asm volatile("s_waitcnt vmcnt(3)" ::: "memory");
        } else {
            asm volatile("s_waitcnt vmcnt(0)" ::: "memory");
        }
        __builtin_amdgcn_s_barrier();
        __builtin_amdgcn_sched_barrier(0);

        bf16x8 af[IT], bfr[4];
#pragma unroll
        for (int i = 0; i < IT; ++i)
            af[i] = *(const bf16x8*)&As[cur * ASZ + (wr * WROWS + i * 16 + lr) * 32 + lg * 8];
#pragma unroll
        for (int j = 0; j < 4; ++j)
            bfr[j] = *(const bf16x8*)&Bs[cur * 4096 + (wc * 64 + j * 16 + lr) * 32 + lg * 8];

        if (t + 2 < NT) {
            int nb = cur + 2; if (nb >= 3) nb -= 3;
            STAGE((t + 2) * 32, nb);
        }

#pragma unroll
        for (int i = 0; i < IT; ++i)
#pragma unroll
            for (int j = 0; j < 4; ++j)
                acc[i][j] = __builtin_amdgcn_mfma_f32_16x16x32_bf16(
                    af[i], bfr[j], acc[i][j], 0, 0, 0);

        cur = (cur == 2) ? 0 : cur + 1;
    }

    for (int i = 0; i < IT; ++i) {
        for (int j = 0; j < 4; ++j) {
            int gcol = n0 + wc * 64 + j * 16 + lr;
            float bv = bias[gcol] * bsc;
            int s0full = row0 + wr * WROWS + i * 16 + lg * 4;
            if (QKV && zz == 1) {
                int b_ = s0full >> 11, sr = s0full & (SEQ - 1);
                int h_ = gcol >> 6, dh = gcol & 63;
                int jt_ = sr >> 6, t0 = sr & 63;
                int tb_ = t0 >> 5, m0 = t0 & 31;
                int dk_ = dh >> 4, hi_ = (dh >> 3) & 1, e_ = dh & 7;
                unsigned short* Kf = (unsigned short*)Cp;
                size_t base = ((size_t)(b_ * NHEADS + h_) * (SEQ >> 6) + jt_) * 4096
                            + (size_t)((tb_ * 4 + dk_) * 64 + hi_ * 32) * 8 + e_;
#pragma unroll
                for (int r = 0; r < 4; ++r)
                    Kf[base + (size_t)(m0 + r) * 8] = f2bf(acc[i][j][r] + bv);
            } else if (QKV && zz == 2) {
                int b_ = s0full >> 11, sr = s0full & (SEQ - 1);
                int h_ = gcol >> 6, dh = gcol & 63;
                int jt_ = sr >> 6, t0 = sr & 63;
                int ts_ = t0 >> 4, hi_ = (t0 >> 3) & 1, e0 = t0 & 7;
                int dblk = dh >> 5, m_ = dh & 31;
                unsigned w0 = (unsigned)f2bf(acc[i][j][0] + bv)
                            | ((unsigned)f2bf(acc[i][j][1] + bv) << 16);
                unsigned w1 = (unsigned)f2bf(acc[i][j][2] + bv)
                            | ((unsigned)f2bf(acc[i][j][3] + bv) << 16);
                unsigned long long pk = (unsigned long long)w0
                                      | ((unsigned long long)w1 << 32);
                unsigned short* Vf = (unsigned short*)Cp;
                size_t idx = ((size_t)(b_ * NHEADS + h_) * (SEQ >> 6) + jt_) * 4096
                           + (size_t)((dblk * 4 + ts_) * 64 + hi_ * 32 + m_) * 8 + e0;
                *(unsigned long long*)&Vf[idx] = pk;
            } else if (DEST == 0) {
#pragma unroll
                for (int r = 0; r < 4; ++r) {
                    int grow = s0full + r;
                    float val = acc[i][j][r] + bv;
                    int b_ = grow >> 11, s = grow & (SEQ - 1);
                    int h_ = gcol >> 6, dh = gcol & 63;
                    ((unsigned short*)Cp)[(((size_t)b_ * NHEADS + h_) * SEQ + s) * DEPTH + dh]
                        = f2bf(val);
                }
            } else {
#pragma unroll
                for (int r = 0; r < 4; ++r) {
                    int grow = s0full + r;
                    ((float*)Cp)[(size_t)grow * N + gcol] = acc[i][j][r] + bv;
                }
            }
        }
    }
}

// -------- causal flash attention: 2 waves/block KV-split, 32 q-rows ----------
// (round-13 config, tree-sum psum)
#define KLOAD(JT, KF)                                                          \
{                                                                              \
    const unsigned short* Kt_ = Kb + (size_t)(JT) * 4096;                      \
    _Pragma("unroll")                                                          \
    for (int f_ = 0; f_ < 8; ++f_)                                             \
        KF[f_] = *(const bf16x8*)&Kt_[(size_t)f_ * 512 + lane * 8];            \
}

#define TILE_BODY(KC, KN)                                                      \
{                                                                              \
    const unsigned short* Vg = Vb + (size_t)jt * 4096;                         \
    bf16x8 vf0[4], vf1[4];                                                     \
    _Pragma("unroll")                                                          \
    for (int ts = 0; ts < 4; ++ts) {                                           \
        vf0[ts] = *(const bf16x8*)&Vg[(size_t)ts * 512 + lane * 8];            \
        vf1[ts] = *(const bf16x8*)&Vg[(size_t)(4 + ts) * 512 + lane * 8];      \
    }                                                                          \
    if (jt + 2 < ntiles) { KLOAD(jt + 2, KN) }                                 \
    f32x16 st[2];                                                              \
    __builtin_amdgcn_s_setprio(1);                                             \
    _Pragma("unroll")                                                          \
    for (int tb = 0; tb < 2; ++tb) {                                           \
        f32x16 a;                                                              \
        _Pragma("unroll") for (int r = 0; r < 16; ++r) a[r] = 0.f;             \
        _Pragma("unroll")                                                      \
        for (int dk = 0; dk < 4; ++dk)                                         \
            a = __builtin_amdgcn_mfma_f32_32x32x16_bf16(KC[tb * 4 + dk], qf[dk], a, 0, 0, 0); \
        st[tb] = a;                                                            \
    }                                                                          \
    __builtin_amdgcn_s_setprio(0);                                             \
    if (jt == ntiles - 1) {                                                    \
        _Pragma("unroll")                                                      \
        for (int tb = 0; tb < 2; ++tb)                                         \
            _Pragma("unroll")                                                  \
            for (int r = 0; r < 16; ++r) {                                     \
                int t = jt * 64 + tb * 32 + (r & 3) + 8 * (r >> 2) + 4 * hi;   \
                if (t > qr0 + m) st[tb][r] = -1e9f;                            \
            }                                                                  \
    }                                                                          \
    float tmx[16];                                                             \
    _Pragma("unroll")                                                          \
    for (int r = 0; r < 16; ++r) tmx[r] = fmaxf(st[0][r], st[1][r]);           \
    _Pragma("unroll")                                                          \
    for (int sft = 8; sft; sft >>= 1)                                          \
        _Pragma("unroll")                                                      \
        for (int r = 0; r < 8; ++r)                                            \
            if (r < sft) tmx[r] = fmaxf(tmx[r], tmx[r + sft]);                 \
    float tmax;                                                                \
    {                                                                          \
        union { float f; unsigned u; } cu_; cu_.f = tmx[0];                    \
        uint2v rr_ = pls(cu_.u, cu_.u);                                        \
        union { unsigned u; float f; } a_, b_; a_.u = rr_[0]; b_.u = rr_[1];   \
        tmax = fmaxf(a_.f, b_.f);                                              \
    }                                                                          \
    if (!__all(tmax <= mrun + DEFER_THR)) {                                    \
        float mnew = fmaxf(mrun, tmax);                                        \
        float sc = exp2f(mrun - mnew);                                         \
        mrun = mnew; lrun *= sc;                                               \
        if (hi == 0) scbw[m] = sc;                                             \
        f32x4 s4[4];                                                           \
        _Pragma("unroll")                                                      \
        for (int g = 0; g < 4; ++g) s4[g] = *(f32x4*)&scbw[g * 8 + hi * 4];    \
        _Pragma("unroll")                                                      \
        for (int r = 0; r < 16; ++r) {                                         \
            float f = s4[r >> 2][r & 3];                                       \
            o0[r] *= f; o1[r] *= f;                                            \
        }                                                                      \
    }                                                                          \
    _Pragma("unroll")                                                          \
    for (int tb = 0; tb < 2; ++tb)                                             \
        _Pragma("unroll")                                                      \
        for (int r = 0; r < 16; ++r)                                           \
            st[tb][r] = exp2f(st[tb][r] - mrun);                               \
    float s16[16];                                                             \
    _Pragma("unroll")                                                          \
    for (int r = 0; r < 16; ++r) s16[r] = st[0][r] + st[1][r];                 \
    _Pragma("unroll")                                                          \
    for (int sft = 8; sft; sft >>= 1)                                          \
        _Pragma("unroll")                                                      \
        for (int r = 0; r < 8; ++r)                                            \
            if (r < sft) s16[r] += s16[r + sft];                               \
    {                                                                          \
        union { float f; unsigned u; } cu_; cu_.f = s16[0];                    \
        uint2v rr_ = pls(cu_.u, cu_.u);                                        \
        union { unsigned u; float f; } a_, b_; a_.u = rr_[0]; b_.u = rr_[1];   \
        lrun += a_.f + b_.f;                                                   \
    }                                                                          \
    unsigned pkw[8][2];                                                        \
    _Pragma("unroll")                                                          \
    for (int G = 0; G < 8; ++G) {                                              \
        const int tb = G >> 2, g = G & 3;                                      \
        pkw[G][0] = cvtpk(st[tb][4 * g + 0], st[tb][4 * g + 1]);               \
        pkw[G][1] = cvtpk(st[tb][4 * g + 2], st[tb][4 * g + 3]);               \
    }                                                                          \
    __builtin_amdgcn_s_setprio(1);                                             \
    _Pragma("unroll")                                                          \
    for (int ts = 0; ts < 4; ++ts) {                                           \
        uint2v s0_ = pls(pkw[2 * ts][0], pkw[2 * ts + 1][0]);                  \
        uint2v s1_ = pls(pkw[2 * ts][1], pkw[2 * ts + 1][1]);                  \
        union { unsigned u[4]; bf16x8 v; } uu;                                 \
        uu.u[0] = s0_[0]; uu.u[1] = s1_[0]; uu.u[2] = s0_[1]; uu.u[3] = s1_[1]; \
        o0 = __builtin_amdgcn_mfma_f32_32x32x16_bf16(uu.v, vf0[ts], o0, 0, 0, 0); \
        o1 = __builtin_amdgcn_mfma_f32_32x32x16_bf16(uu.v, vf1[ts], o1, 0, 0, 0); \
    }                                                                          \
    __builtin_amdgcn_s_setprio(0);                                             \
}

__global__ __launch_bounds__(128, 2) void attn_wave(
    const unsigned short* __restrict__ Qh, const unsigned short* __restrict__ Kh,
    const unsigned short* __restrict__ Vt, unsigned short* __restrict__ ctx)
{
    __shared__ __align__(16) float scb[2][32];
    __shared__ __align__(16) float mlbuf[2][2][32];
    __shared__ __align__(16) float c0b[32], c1b[32], invb[32];
    __shared__ __align__(16) float osh0[16][64], osh1[16][64];

    const int tid  = threadIdx.x;
    const int ww   = tid >> 6;
    const int lane = tid & 63;
    const int m    = lane & 31;
    const int hi   = lane >> 5;
    float* scbw = scb[ww];

    const int bid  = blockIdx.x;
    const int bh   = bid & 31;
    const int qb   = 63 - (bid >> 5);
    const int qr0  = qb * 32;

    const int b = bh >> 4, h = bh & 15;
    const unsigned short* Qb = Qh + ((size_t)bh * SEQ + qr0) * DEPTH;
    const unsigned short* Kb = Kh + (size_t)bh * SEQ * DEPTH;
    const unsigned short* Vb = Vt + (size_t)bh * SEQ * DEPTH;

    bf16x8 qf[4];
#pragma unroll
    for (int dk = 0; dk < 4; ++dk)
        qf[dk] = *(const bf16x8*)&Qb[(size_t)m * DEPTH + dk * 16 + hi * 8];

    f32x16 o0, o1;
#pragma unroll
    for (int r = 0; r < 16; ++r) { o0[r] = 0.f; o1[r] = 0.f; }
    float mrun = -1e30f, lrun = 0.f;

    const int ntiles = (qb >> 1) + 1;
    bf16x8 kfA[8], kfB[8];

    int jt = ww;
    if (jt < ntiles) {
        KLOAD(jt, kfA)
        while (true) {
            TILE_BODY(kfA, kfB)
            jt += 2; if (jt >= ntiles) break;
            TILE_BODY(kfB, kfA)
            jt += 2; if (jt >= ntiles) break;
        }
    }

    if (hi == 0) { mlbuf[ww][0][m] = mrun; mlbuf[ww][1][m] = lrun; }
    __syncthreads();
    if (ww == 0 && hi == 0) {
        float m0 = mlbuf[0][0][m], l0 = mlbuf[0][1][m];
        float m1 = mlbuf[1][0][m], l1 = mlbuf[1][1][m];
        float M  = fmaxf(m0, m1);
        float c0 = exp2f(m0 - M), c1 = exp2f(m1 - M);
        c0b[m] = c0; c1b[m] = c1;
        invb[m] = 1.0f / (l0 * c0 + l1 * c1);
    }
    __syncthreads();

    const float* cb = (ww == 0) ? c0b : c1b;
    f32x4 fc[4];
#pragma unroll
    for (int g = 0; g < 4; ++g)
        fc[g] = *(const f32x4*)&cb[g * 8 + hi * 4];
#pragma unroll
    for (int r = 0; r < 16; ++r) {
        float f = fc[r >> 2][r & 3];
        o0[r] *= f; o1[r] *= f;
    }
    if (ww == 0) {
#pragma unroll
        for (int r = 0; r < 16; ++r) { osh0[r][lane] = o0[r]; osh1[r][lane] = o1[r]; }
    }
    __syncthreads();
    if (ww == 1) {
        f32x4 fi[4];
#pragma unroll
        for (int g = 0; g < 4; ++g)
            fi[g] = *(const f32x4*)&invb[g * 8 + hi * 4];
#pragma unroll
        for (int r = 0; r < 16; ++r) {
            float inv = fi[r >> 2][r & 3];
            int ml = (r & 3) + 8 * (r >> 2) + 4 * hi;
            size_t rowbase = ((size_t)b * SEQ + qr0 + ml) * D_MODEL + h * DEPTH;
            ctx[rowbase + m]      = f2bf((o0[r] + osh0[r][lane]) * inv);
            ctx[rowbase + 32 + m] = f2bf((o1[r] + osh1[r][lane]) * inv);
        }
    }
}

extern "C" void kernel_launch(void* const* d_in, const int* in_sizes, int n_in,
                              void* d_out, int out_size, void* d_ws, size_t ws_size,
                              hipStream_t stream) {
    const float* v  = (const float*)d_in[0];
    const float* k  = (const float*)d_in[1];
    const float* q  = (const float*)d_in[2];
    // d_in[3] = mask (causal, implemented analytically)
    const float* Wq = (const float*)d_in[4];
    const float* bq = (const float*)d_in[5];
    const float* Wk = (const float*)d_in[6];
    const float* bk = (const float*)d_in[7];
    const float* Wv = (const float*)d_in[8];
    const float* bv = (const float*)d_in[9];
    const float* Wo = (const float*)d_in[10];
    const float* bo = (const float*)d_in[11];

    char* ws = (char*)d_ws;
    const size_t MB = 1024 * 1024;
    unsigned short* Qb  = (unsigned short*)(ws + 0);        // 8 MB (aliased by ctx)
    unsigned short* Kb  = (unsigned short*)(ws + 8  * MB);
    unsigned short* Vb  = (unsigned short*)(ws + 16 * MB);
    unsigned short* Wqb = (unsigned short*)(ws + 24 * MB);  // 2 MB each
    unsigned short* Wkb = (unsigned short*)(ws + 26 * MB);
    unsigned short* Wvb = (unsigned short*)(ws + 28 * MB);
    unsigned short* Wob = (unsigned short*)(ws + 30 * MB);
    unsigned short* Qh  = (unsigned short*)(ws + 32 * MB);  // 8 MB each
    unsigned short* Kh  = (unsigned short*)(ws + 40 * MB);
    unsigned short* Vtt = (unsigned short*)(ws + 48 * MB);
    unsigned short* ctx = Qb;   // Qb dead once projections finish

    convert_bf16<<<2048, 256, 0, stream>>>(q, k, v, Wq, Wk, Wv, Wo,
                                           Qb, Kb, Vb, Wqb, Wkb, Wvb, Wob);

    // QKV projections: grid (rowpanels=32, npanels=8, 3) -> A-panel XCD affinity
    gemm_bf16<4, 0, true><<<dim3(32, 8, 3), 256, 0, stream>>>(
        Qb, Kb, Vb, Wqb, Wkb, Wvb, bq, bk, bv,
        (void*)Qh, (void*)Kh, (void*)Vtt, NTOK, D_MODEL, D_MODEL);

    attn_wave<<<dim3(2048), 128, 0, stream>>>(Qh, Kh, Vtt, ctx);

    // output projection: grid (rowpanels=64, npanels=8)
    gemm_bf16<2, 1, false><<<dim3(64, 8), 256, 0, stream>>>(
        ctx, nullptr, nullptr, Wob, nullptr, nullptr, bo, nullptr, nullptr,
        d_out, nullptr, nullptr, NTOK, D_MODEL, D_MODEL);
}